// Round 1
// baseline (188.676 us; speedup 1.0000x reference)
//
#include <hip/hip_runtime.h>

// LTU: out[i] = (dot(W[i,:], x) < 0.6*4096 - negcount(W[i,:])) ? 0 : 1
// W: 8192 x 4096 fp32 row-major, x: 4096 fp32, out: 8192 fp32.
// One wave (64 lanes) per row; float4 coalesced loads; shfl reduction.

#define N_TL1 8192
#define N_INP 4096

__global__ __launch_bounds__(256) void LTU_kernel(const float* __restrict__ x,
                                                  const float* __restrict__ W,
                                                  float* __restrict__ out) {
    const int wave = threadIdx.x >> 6;          // 0..3
    const int lane = threadIdx.x & 63;
    const int row  = blockIdx.x * 4 + wave;     // grid = 8192/4 = 2048

    const float4* __restrict__ Wrow = (const float4*)(W + (size_t)row * N_INP);
    const float4* __restrict__ xv   = (const float4*)x;

    float acc = 0.0f;
    int   cnt = 0;

    // 4096 floats = 1024 float4 per row; 64 lanes -> 16 iterations.
    #pragma unroll
    for (int it = 0; it < N_INP / 4 / 64; ++it) {
        const int idx = it * 64 + lane;
        float4 w  = Wrow[idx];
        float4 xx = xv[idx];
        acc += w.x * xx.x + w.y * xx.y + w.z * xx.z + w.w * xx.w;
        cnt += (w.x < 0.0f) + (w.y < 0.0f) + (w.z < 0.0f) + (w.w < 0.0f);
    }

    // wave-64 butterfly reduction of (acc, cnt)
    #pragma unroll
    for (int off = 32; off > 0; off >>= 1) {
        acc += __shfl_down(acc, off, 64);
        cnt += __shfl_down(cnt, off, 64);
    }

    if (lane == 0) {
        const float tau = 0.6f * (float)N_INP - (float)cnt;
        out[row] = (acc < tau) ? 0.0f : 1.0f;
    }
}

extern "C" void kernel_launch(void* const* d_in, const int* in_sizes, int n_in,
                              void* d_out, int out_size, void* d_ws, size_t ws_size,
                              hipStream_t stream) {
    const float* x = (const float*)d_in[0];   // [4096,1]
    const float* W = (const float*)d_in[1];   // [8192,4096]
    float* out = (float*)d_out;               // [8192]

    dim3 grid(N_TL1 / 4);
    dim3 block(256);
    LTU_kernel<<<grid, block, 0, stream>>>(x, W, out);
}

// Round 3
// 180.440 us; speedup vs baseline: 1.0456x; 1.0456x over previous
//
#include <hip/hip_runtime.h>

// LTU: out[i] = (dot(W[i,:], x) < 0.6*4096 - negcount(W[i,:])) ? 0 : 1
// W: 8192 x 4096 fp32 row-major, x: 4096 fp32, out: 8192 fp32.
// R3: 2 rows per wave (amortize x loads), nontemporal W loads via native
// clang vector type (HIP_vector_type rejected by the builtin),
// __launch_bounds__(256,4) keeps 4 blocks/CU.

#define N_TL1 8192
#define N_INP 4096
#define ROWS_PER_WAVE 2

typedef float vfloat4 __attribute__((ext_vector_type(4)));

__global__ __launch_bounds__(256, 4) void LTU_kernel(const float* __restrict__ x,
                                                     const float* __restrict__ W,
                                                     float* __restrict__ out) {
    const int wave = threadIdx.x >> 6;                         // 0..3
    const int lane = threadIdx.x & 63;
    const int row0 = (blockIdx.x * 4 + wave) * ROWS_PER_WAVE;  // grid = 1024

    const vfloat4* __restrict__ W0 = (const vfloat4*)(W + (size_t)row0 * N_INP);
    const vfloat4* __restrict__ W1 = (const vfloat4*)(W + (size_t)(row0 + 1) * N_INP);
    const vfloat4* __restrict__ xv = (const vfloat4*)x;

    float acc0 = 0.0f, acc1 = 0.0f;
    int   cnt0 = 0,    cnt1 = 0;

    // 1024 vfloat4 per row; 64 lanes -> 16 chunks per row.
    #pragma unroll 4
    for (int it = 0; it < N_INP / 4 / 64; ++it) {
        const int idx = it * 64 + lane;
        vfloat4 xx = xv[idx];
        vfloat4 w0 = __builtin_nontemporal_load(&W0[idx]);
        vfloat4 w1 = __builtin_nontemporal_load(&W1[idx]);
        acc0 += w0.x * xx.x + w0.y * xx.y + w0.z * xx.z + w0.w * xx.w;
        cnt0 += (w0.x < 0.0f) + (w0.y < 0.0f) + (w0.z < 0.0f) + (w0.w < 0.0f);
        acc1 += w1.x * xx.x + w1.y * xx.y + w1.z * xx.z + w1.w * xx.w;
        cnt1 += (w1.x < 0.0f) + (w1.y < 0.0f) + (w1.z < 0.0f) + (w1.w < 0.0f);
    }

    // wave-64 butterfly reduction
    #pragma unroll
    for (int off = 32; off > 0; off >>= 1) {
        acc0 += __shfl_down(acc0, off, 64);
        cnt0 += __shfl_down(cnt0, off, 64);
        acc1 += __shfl_down(acc1, off, 64);
        cnt1 += __shfl_down(cnt1, off, 64);
    }

    if (lane == 0) {
        const float tau0 = 0.6f * (float)N_INP - (float)cnt0;
        const float tau1 = 0.6f * (float)N_INP - (float)cnt1;
        out[row0]     = (acc0 < tau0) ? 0.0f : 1.0f;
        out[row0 + 1] = (acc1 < tau1) ? 0.0f : 1.0f;
    }
}

extern "C" void kernel_launch(void* const* d_in, const int* in_sizes, int n_in,
                              void* d_out, int out_size, void* d_ws, size_t ws_size,
                              hipStream_t stream) {
    const float* x = (const float*)d_in[0];   // [4096,1]
    const float* W = (const float*)d_in[1];   // [8192,4096]
    float* out = (float*)d_out;               // [8192]

    dim3 grid(N_TL1 / (4 * ROWS_PER_WAVE));   // 1024
    dim3 block(256);
    LTU_kernel<<<grid, block, 0, stream>>>(x, W, out);
}